// Round 1
// 124.733 us; speedup vs baseline: 1.0256x; 1.0256x over previous
//
#include <hip/hip_runtime.h>

// Problem constants: x [8,128,96,96] fp32, W [384,128] fp32, out [8,128,96,96] fp32.
#define NB     8
#define CIN    128
#define HEADS  4
#define DHEAD  32
#define HDIM   96
#define WDIM   96
#define HW     9216
#define TP     64    // positions per stage-1 block

typedef __bf16 bf16x8 __attribute__((ext_vector_type(8)));
typedef float  f32x4  __attribute__((ext_vector_type(4)));

__device__ __forceinline__ unsigned f2bf(float f) {
  unsigned u = __float_as_uint(f);
  return (u + 0x7fffu + ((u >> 16) & 1u)) >> 16;   // RNE
}
__device__ __forceinline__ unsigned pack2(float a, float b) {
  return f2bf(a) | (f2bf(b) << 16);
}
__device__ __forceinline__ float bflo(unsigned u) { return __uint_as_float(u << 16); }
__device__ __forceinline__ float bfhi(unsigned u) { return __uint_as_float(u & 0xffff0000u); }

// ---------------------------------------------------------------------------
// Prep: pack W [384][128] fp32 into A-fragment-ordered bf16 global buffer.
// Frag (ot,kb): lane l holds A[o=ot*16+(l&15)][c=kb*32+(l>>4)*8+j], j=0..7 (16B).
// ---------------------------------------------------------------------------
__global__ __launch_bounds__(256) void wpack_kernel(const float* __restrict__ W,
                                                    uint4* __restrict__ Wf) {
  const int u = blockIdx.x * 256 + threadIdx.x;   // 0..6143 = 24 ot * 4 kb * 64 lanes
  const int lane = u & 63, kb = (u >> 6) & 3, ot = u >> 8;
  const int o = ot * 16 + (lane & 15);
  const int c0 = kb * 32 + (lane >> 4) * 8;
  const float4* w = (const float4*)(W + (size_t)o * CIN + c0);
  float4 w0 = w[0], w1 = w[1];
  uint4 r;
  r.x = pack2(w0.x, w0.y); r.y = pack2(w0.z, w0.w);
  r.z = pack2(w1.x, w1.y); r.w = pack2(w1.z, w1.w);
  Wf[u] = r;
}

// ---------------------------------------------------------------------------
// Stage 1: QKV projection via bf16 MFMA. C[o][p] = sum_c W[o][c] * x[c][p].
// qkv layout: [which(3)][b][g(4)][p(9216)][d(32)] bf16.
// ---------------------------------------------------------------------------
__global__ __launch_bounds__(256) void qkv_kernel(const float* __restrict__ x,
                                                  const uint4* __restrict__ Wf,
                                                  unsigned short* __restrict__ qkvb) {
  // B-frags for 4 p-tiles x 4 k-blocks, 64 lanes x 16B each = 16 KB
  __shared__ uint4 xs[16 * 64];
  const int b  = blockIdx.y;
  const int p0 = blockIdx.x * TP;
  const int t  = threadIdx.x;

  // ---- load x tile [128 c][64 p], convert bf16, store in B-frag order ----
  {
    const int p = t & 63, cg_hi = t >> 6;
    const int pt = p >> 4, n = p & 15;
    const float* xb = x + (size_t)b * CIN * HW + p0 + p;
#pragma unroll
    for (int i = 0; i < 4; ++i) {
      const int cg = i * 4 + cg_hi;        // 0..15 (octet of channels)
      const int c0 = cg * 8;
      const int kb = cg >> 2, q = cg & 3;
      float f[8];
#pragma unroll
      for (int j = 0; j < 8; ++j) f[j] = xb[(size_t)(c0 + j) * HW];  // coalesced
      uint4 r;
      r.x = pack2(f[0], f[1]); r.y = pack2(f[2], f[3]);
      r.z = pack2(f[4], f[5]); r.w = pack2(f[6], f[7]);
      xs[(pt * 4 + kb) * 64 + q * 16 + n] = r;
    }
  }
  __syncthreads();

  // ---- compute: wave wv covers o-tiles 6*wv .. 6*wv+5, all 4 p-tiles ----
  const int wv = t >> 6, lane = t & 63;
  const int colp = lane & 15, quad = lane >> 4;
#pragma unroll 1
  for (int it = 0; it < 6; ++it) {
    const int ot = wv * 6 + it;
    bf16x8 afrag[4];
#pragma unroll
    for (int kb = 0; kb < 4; ++kb) {
      uint4 tmp = Wf[(ot * 4 + kb) * 64 + lane];   // L2-hot, coalesced
      afrag[kb] = *(bf16x8*)&tmp;
    }
    const int o0 = ot * 16 + quad * 4;             // 4 consecutive o for regs 0..3
    const int which = o0 >> 7, g = (o0 & 127) >> 5, d0 = o0 & 31;
    unsigned short* dst = qkvb
        + (((size_t)(which * NB + b) * HEADS + g) * HW) * DHEAD + d0;
#pragma unroll
    for (int pt = 0; pt < 4; ++pt) {
      f32x4 acc = {0.f, 0.f, 0.f, 0.f};
#pragma unroll
      for (int kb = 0; kb < 4; ++kb) {
        bf16x8 bfrag = *(bf16x8*)&xs[(pt * 4 + kb) * 64 + lane];
        acc = __builtin_amdgcn_mfma_f32_16x16x32_bf16(afrag[kb], bfrag, acc, 0, 0, 0);
      }
      const int pp = p0 + pt * 16 + colp;
      uint2 st;                                     // d0..d0+3 as bf16x4
      st.x = pack2(acc[0], acc[1]);
      st.y = pack2(acc[2], acc[3]);
      *(uint2*)(dst + (size_t)pp * DHEAD) = st;
    }
  }
}

// ---------------------------------------------------------------------------
// Stage 2: 3x3 neighborhood attention, bf16 qkv in, fp32 out.
// Tile 32(w) x 8(h) per block for one (b,g). K/V halo (10x34) staged in LDS
// via coalesced uint4 loads; OOB positions zero-filled (=> logit exactly 0,
// V contribution 0 -- matches reference zero-pad semantics branch-free).
// LDS layout chunk-planar [chunk(4)][pos]: a wave's ds_read_b128 at
// consecutive pos lands slot = pos mod 8 -> conflict-free.
// ---------------------------------------------------------------------------
#define KROWS 10
#define KCOLS 34
#define KPOS  (KROWS * KCOLS)   // 340
#define QPOS  256

__global__ __launch_bounds__(256) void attn_kernel(const unsigned short* __restrict__ qkvb,
                                                   float* __restrict__ out) {
  __shared__ uint4 qs[4 * QPOS];   // 16 KB
  __shared__ uint4 ks[4 * KPOS];   // 21.25 KB
  __shared__ uint4 vs[4 * KPOS];   // 21.25 KB  (total 59.9 KB -> 2 blocks/CU)

  const int bg = blockIdx.z;                        // b*4+g
  const int h0 = blockIdx.y * 8;
  const int w0 = blockIdx.x * 32;
  const int x  = threadIdx.x, y = threadIdx.y;
  const int t  = y * 32 + x;
  const int b  = bg >> 2, g = bg & 3;

  const size_t plane = (size_t)HW * DHEAD;          // in ushorts
  const uint4* Qg = (const uint4*)(qkvb + (size_t)bg * plane);
  const uint4* Kg = (const uint4*)(qkvb + (size_t)(32 + bg) * plane);
  const uint4* Vg = (const uint4*)(qkvb + (size_t)(64 + bg) * plane);

  // ---- stage Q tile: 8 rows x 32 pos x 4 chunks = 1024 chunks (coalesced) ----
  {
    int u = t;
#pragma unroll
    for (int it = 0; it < 4; ++it, u += 256) {
      const int r = u >> 7, j = u & 127;            // j = col*4 + chunk
      const int col = j >> 2, c = j & 3;
      const int p = (h0 + r) * WDIM + w0 + col;
      qs[c * QPOS + r * 32 + col] = Qg[(size_t)p * 4 + c];
    }
  }
  // ---- stage K,V halo: 10 rows x 34 pos x 4 chunks = 1360 chunks each ----
  for (int u = t; u < KPOS * 4; u += 256) {
    const int r = u / 136;                          // halo row 0..9
    const int j = u - r * 136;                      // cc*4 + chunk
    const int cc = j >> 2, c = j & 3;
    const int hh = h0 - 1 + r, ww = w0 - 1 + cc;
    uint4 kk = {0u, 0u, 0u, 0u}, vv = {0u, 0u, 0u, 0u};
    if (hh >= 0 && hh < HDIM && ww >= 0 && ww < WDIM) {
      const size_t p = (size_t)(hh * WDIM + ww) * 4 + c;
      kk = Kg[p];
      vv = Vg[p];
    }
    const int dst = c * KPOS + r * KCOLS + cc;
    ks[dst] = kk;
    vs[dst] = vv;
  }
  __syncthreads();

  // ---- unpack own Q ----
  float q[32];
#pragma unroll
  for (int c = 0; c < 4; ++c) {
    uint4 u = qs[c * QPOS + t];
    q[c * 8 + 0] = bflo(u.x); q[c * 8 + 1] = bfhi(u.x);
    q[c * 8 + 2] = bflo(u.y); q[c * 8 + 3] = bfhi(u.y);
    q[c * 8 + 4] = bflo(u.z); q[c * 8 + 5] = bfhi(u.z);
    q[c * 8 + 6] = bflo(u.w); q[c * 8 + 7] = bfhi(u.w);
  }

  const int pbase = (y + 1) * KCOLS + (x + 1);

  // ---- logits (OOB neighbors read zeros -> dot == 0 exactly) ----
  float att[9];
#pragma unroll
  for (int nn = 0; nn < 9; ++nn) {
    const int pn = pbase + (nn / 3 - 1) * KCOLS + (nn % 3 - 1);
    float dot = 0.0f;
#pragma unroll
    for (int c = 0; c < 4; ++c) {
      uint4 u = ks[c * KPOS + pn];
      dot = fmaf(q[c * 8 + 0], bflo(u.x), dot);
      dot = fmaf(q[c * 8 + 1], bfhi(u.x), dot);
      dot = fmaf(q[c * 8 + 2], bflo(u.y), dot);
      dot = fmaf(q[c * 8 + 3], bfhi(u.y), dot);
      dot = fmaf(q[c * 8 + 4], bflo(u.z), dot);
      dot = fmaf(q[c * 8 + 5], bfhi(u.z), dot);
      dot = fmaf(q[c * 8 + 6], bflo(u.w), dot);
      dot = fmaf(q[c * 8 + 7], bfhi(u.w), dot);
    }
    att[nn] = dot * 0.17677669529663687f;   // 1/sqrt(32)
  }

  // ---- softmax over 9 ----
  float m = att[0];
#pragma unroll
  for (int nn = 1; nn < 9; ++nn) m = fmaxf(m, att[nn]);
  float s = 0.0f;
#pragma unroll
  for (int nn = 0; nn < 9; ++nn) { att[nn] = __expf(att[nn] - m); s += att[nn]; }
  const float inv = 1.0f / s;

  // ---- PV (OOB neighbors: V == 0 -> contributes nothing) ----
  float acc[32];
#pragma unroll
  for (int i = 0; i < 32; ++i) acc[i] = 0.0f;
#pragma unroll
  for (int nn = 0; nn < 9; ++nn) {
    const float wn = att[nn] * inv;
    const int pn = pbase + (nn / 3 - 1) * KCOLS + (nn % 3 - 1);
#pragma unroll
    for (int c = 0; c < 4; ++c) {
      uint4 u = vs[c * KPOS + pn];
      acc[c * 8 + 0] = fmaf(wn, bflo(u.x), acc[c * 8 + 0]);
      acc[c * 8 + 1] = fmaf(wn, bfhi(u.x), acc[c * 8 + 1]);
      acc[c * 8 + 2] = fmaf(wn, bflo(u.y), acc[c * 8 + 2]);
      acc[c * 8 + 3] = fmaf(wn, bfhi(u.y), acc[c * 8 + 3]);
      acc[c * 8 + 4] = fmaf(wn, bflo(u.z), acc[c * 8 + 4]);
      acc[c * 8 + 5] = fmaf(wn, bfhi(u.z), acc[c * 8 + 5]);
      acc[c * 8 + 6] = fmaf(wn, bflo(u.w), acc[c * 8 + 6]);
      acc[c * 8 + 7] = fmaf(wn, bfhi(u.w), acc[c * 8 + 7]);
    }
  }

  // out [b][C=128][96][96]; channel = g*32 + d; lanes along w -> coalesced
  const int p = (h0 + y) * WDIM + (w0 + x);
  float* ob = out + ((size_t)b * CIN + (size_t)g * DHEAD) * HW + p;
#pragma unroll
  for (int i = 0; i < 32; ++i) ob[(size_t)i * HW] = acc[i];
}

extern "C" void kernel_launch(void* const* d_in, const int* in_sizes, int n_in,
                              void* d_out, int out_size, void* d_ws, size_t ws_size,
                              hipStream_t stream) {
  (void)in_sizes; (void)n_in; (void)out_size; (void)ws_size;
  const float* x = (const float*)d_in[0];   // [8,128,96,96]
  const float* W = (const float*)d_in[1];   // [384,128]
  float* out = (float*)d_out;

  const size_t qkv_ushorts = (size_t)3 * NB * HEADS * HW * DHEAD;  // 28.3M -> 56.6 MB
  unsigned short* qkvb = (unsigned short*)d_ws;
  uint4* Wf = (uint4*)((char*)d_ws + qkv_ushorts * 2);             // 98 KB more

  wpack_kernel<<<24, 256, 0, stream>>>(W, Wf);
  qkv_kernel<<<dim3(HW / TP, NB), 256, 0, stream>>>(x, Wf, qkvb);
  attn_kernel<<<dim3(WDIM / 32, HDIM / 8, NB * HEADS), dim3(32, 8, 1), 0, stream>>>(qkvb, out);
}